// Round 1
// baseline (25.725 us; speedup 1.0000x reference)
//
#include <hip/hip_runtime.h>

// GaussianCategoricalSampler:
//   pattern [1,4,8,16] x16  -> 64 output columns, 480 input columns per row.
//   size<=1: consumes 2 cols, emits col0 (mu).
//   size>1 : consumes size cols, emits argmax (softmax->clip->renorm is
//            weakly monotone, so argmax of raw logits, first-max tie-break).

constexpr int WIDTH   = 480;   // input columns per row
constexpr int NOUT    = 64;    // output columns per row
constexpr int ROWS    = 32;    // rows staged per block
constexpr int THREADS = 256;
constexpr int STRIDE  = 481;   // LDS row stride (+1 pad: read-phase banks 2-way max)

template <int N>
__device__ __forceinline__ float argmaxN(const float* __restrict__ p) {
    float best = p[0];
    int   bi   = 0;
#pragma unroll
    for (int i = 1; i < N; ++i) {
        if (p[i] > best) { best = p[i]; bi = i; }  // strict > == first-max (jnp.argmax)
    }
    return (float)bi;
}

__global__ __launch_bounds__(THREADS)
void gcs_kernel(const float* __restrict__ in, float* __restrict__ out) {
    __shared__ float lds[ROWS * STRIDE];

    const int    tid      = threadIdx.x;
    const size_t base_row = (size_t)blockIdx.x * ROWS;

    // ---- Stage 32 rows (15360 floats, contiguous) via coalesced float4 loads.
    const float4* gsrc = reinterpret_cast<const float4*>(in + base_row * WIDTH);
#pragma unroll
    for (int k = 0; k < 15; ++k) {
        int    ch  = tid + k * THREADS;      // chunk id 0..3839 (120 chunks/row)
        float4 v   = gsrc[ch];
        int    row = ch / 120;               // chunks never cross a row (480 % 4 == 0)
        int    col = (ch - row * 120) * 4;
        float* d   = &lds[row * STRIDE + col];
        d[0] = v.x; d[1] = v.y; d[2] = v.z; d[3] = v.w;
    }
    __syncthreads();

    // ---- Compute: thread = (row-in-block, entry-octet). Octet = 2 pattern
    //      groups [1,4,8,16] = 60 input floats -> 8 outputs.
    const int rb = tid >> 3;   // 0..31
    const int eg = tid & 7;    // 0..7
    const float* w = &lds[rb * STRIDE + eg * 60];

    float o[8];
    o[0] = w[0];                  // mu      (cols 0..1)
    o[1] = argmaxN<4>(w + 2);     // size 4  (cols 2..5)
    o[2] = argmaxN<8>(w + 6);     // size 8  (cols 6..13)
    o[3] = argmaxN<16>(w + 14);   // size 16 (cols 14..29)
    o[4] = w[30];
    o[5] = argmaxN<4>(w + 32);
    o[6] = argmaxN<8>(w + 36);
    o[7] = argmaxN<16>(w + 44);

    // ---- Coalesced output: 8 consecutive floats per thread, 2x float4.
    float4* dst = reinterpret_cast<float4*>(out + (base_row + rb) * NOUT + eg * 8);
    dst[0] = make_float4(o[0], o[1], o[2], o[3]);
    dst[1] = make_float4(o[4], o[5], o[6], o[7]);
}

extern "C" void kernel_launch(void* const* d_in, const int* in_sizes, int n_in,
                              void* d_out, int out_size, void* d_ws, size_t ws_size,
                              hipStream_t stream) {
    const float* in  = (const float*)d_in[0];
    float*       out = (float*)d_out;

    int batch  = in_sizes[0] / WIDTH;  // 65536
    int blocks = batch / ROWS;         // 2048

    gcs_kernel<<<blocks, THREADS, 0, stream>>>(in, out);
}